// Round 1
// baseline (1612.216 us; speedup 1.0000x reference)
//
#include <hip/hip_runtime.h>
#include <hip/hip_bf16.h>

#define IN_DIM 64
#define N_TOK 8
#define OUT_DIM 64      // N_HEADS * HEAD_DIM
#define HEAD_DIM 16
#define N_HEADS 4

// ---------------------------------------------------------------------------
// CSR build kernels
// ---------------------------------------------------------------------------
__global__ void zero_kernel(int* p, int n) {
    int i = blockIdx.x * blockDim.x + threadIdx.x;
    if (i < n) p[i] = 0;
}

__global__ void hist_kernel(const int* __restrict__ dst, int* __restrict__ deg, int n) {
    int i = blockIdx.x * blockDim.x + threadIdx.x;
    if (i < n) atomicAdd(&deg[dst[i]], 1);
}

// single-block exclusive scan over deg[0..n), writes offs[0..n] and cur[0..n)
__global__ void scan_kernel(const int* __restrict__ deg, int* __restrict__ offs,
                            int* __restrict__ cur, int n) {
    __shared__ int buf[1024];
    __shared__ int carry;
    const int tid = threadIdx.x;
    if (tid == 0) carry = 0;
    __syncthreads();
    for (int base = 0; base < n; base += 1024) {
        int i = base + tid;
        int v = (i < n) ? deg[i] : 0;
        buf[tid] = v;
        __syncthreads();
        for (int off = 1; off < 1024; off <<= 1) {
            int t = (tid >= off) ? buf[tid - off] : 0;
            __syncthreads();
            buf[tid] += t;
            __syncthreads();
        }
        int incl = buf[tid];
        int excl = incl - v + carry;
        if (i < n) { offs[i] = excl; cur[i] = excl; }
        __syncthreads();                 // everyone done reading carry & buf
        if (tid == 0) carry += buf[1023];
        __syncthreads();
    }
    if (tid == 0) offs[n] = carry;
}

__global__ void scatter_kernel(const int* __restrict__ dst, int* __restrict__ cur,
                               int* __restrict__ csr, int n) {
    int i = blockIdx.x * blockDim.x + threadIdx.x;
    if (i < n) {
        int pos = atomicAdd(&cur[dst[i]], 1);
        csr[pos] = i;
    }
}

// ---------------------------------------------------------------------------
// Projection: one thread owns one row (64 in -> 64 out), W via uniform loads
// ---------------------------------------------------------------------------
__device__ __forceinline__ void proj_row(const float* __restrict__ x,
                                         const float* __restrict__ W,
                                         const float* __restrict__ b,
                                         float scale,
                                         float* __restrict__ out_row) {
    float acc[OUT_DIM];
#pragma unroll
    for (int d = 0; d < OUT_DIM; ++d) acc[d] = b[d];
#pragma unroll 1
    for (int c4 = 0; c4 < IN_DIM / 4; ++c4) {
        const float4 xv = *reinterpret_cast<const float4*>(x + c4 * 4);
#pragma unroll
        for (int j = 0; j < 4; ++j) {
            const float xc = (&xv.x)[j];
            const float* wrow = W + (c4 * 4 + j) * OUT_DIM;   // uniform -> s_load
#pragma unroll
            for (int d = 0; d < OUT_DIM; ++d)
                acc[d] = fmaf(xc, wrow[d], acc[d]);
        }
    }
#pragma unroll
    for (int d4 = 0; d4 < OUT_DIM / 4; ++d4) {
        float4 o;
        o.x = acc[d4 * 4 + 0] * scale;
        o.y = acc[d4 * 4 + 1] * scale;
        o.z = acc[d4 * 4 + 2] * scale;
        o.w = acc[d4 * 4 + 3] * scale;
        *reinterpret_cast<float4*>(out_row + d4 * 4) = o;
    }
}

__global__ void __launch_bounds__(256) hproj_kernel(
    const float* __restrict__ h,
    const float* __restrict__ Qw, const float* __restrict__ Qb,
    const float* __restrict__ Kw, const float* __restrict__ Kb,
    const float* __restrict__ Vw, const float* __restrict__ Vb,
    float* __restrict__ Qh, float* __restrict__ Kh, float* __restrict__ Vh,
    int nrows) {
    int r = blockIdx.x * blockDim.x + threadIdx.x;
    if (r >= nrows) return;
    const float* x = h + (size_t)r * IN_DIM;
    proj_row(x, Qw, Qb, 0.25f, Qh + (size_t)r * OUT_DIM);  // fold 1/sqrt(16) into Q
    proj_row(x, Kw, Kb, 1.0f,  Kh + (size_t)r * OUT_DIM);
    proj_row(x, Vw, Vb, 1.0f,  Vh + (size_t)r * OUT_DIM);
}

// ---------------------------------------------------------------------------
// Fused edge kernel: one thread owns one (edge, tok) pair.
//   pe = e @ Ew + Eb ; score = Kh[src]*Qh_scaled[dst] + pe -> e_out
//   s[h] = exp(clip(sum_d score[h][:], -5, 5)) -> s_buf
// ---------------------------------------------------------------------------
__global__ void __launch_bounds__(256) edge_kernel(
    const float* __restrict__ e,
    const int* __restrict__ src, const int* __restrict__ dst,
    const float* __restrict__ Ew, const float* __restrict__ Eb,
    const float* __restrict__ Qh, const float* __restrict__ Kh,
    float* __restrict__ e_out, float* __restrict__ s_buf,
    int npairs) {
    int p = blockIdx.x * blockDim.x + threadIdx.x;
    if (p >= npairs) return;
    const int eidx = p >> 3;
    const int tok = p & 7;
    const int s_i = src[eidx];
    const int d_i = dst[eidx];

    float acc[OUT_DIM];
#pragma unroll
    for (int d = 0; d < OUT_DIM; ++d) acc[d] = Eb[d];

    const float* erow = e + (size_t)p * IN_DIM;
#pragma unroll 1
    for (int c4 = 0; c4 < IN_DIM / 4; ++c4) {
        const float4 ev = *reinterpret_cast<const float4*>(erow + c4 * 4);
#pragma unroll
        for (int j = 0; j < 4; ++j) {
            const float ec = (&ev.x)[j];
            const float* wrow = Ew + (c4 * 4 + j) * OUT_DIM;   // uniform -> s_load
#pragma unroll
            for (int d = 0; d < OUT_DIM; ++d)
                acc[d] = fmaf(ec, wrow[d], acc[d]);
        }
    }

    const float* krow = Kh + ((size_t)s_i * N_TOK + tok) * OUT_DIM;
    const float* qrow = Qh + ((size_t)d_i * N_TOK + tok) * OUT_DIM;
    float* orow = e_out + (size_t)p * OUT_DIM;
#pragma unroll
    for (int c4 = 0; c4 < OUT_DIM / 4; ++c4) {
        const float4 kv = *reinterpret_cast<const float4*>(krow + c4 * 4);
        const float4 qv = *reinterpret_cast<const float4*>(qrow + c4 * 4);
        acc[c4 * 4 + 0] = fmaf(kv.x, qv.x, acc[c4 * 4 + 0]);
        acc[c4 * 4 + 1] = fmaf(kv.y, qv.y, acc[c4 * 4 + 1]);
        acc[c4 * 4 + 2] = fmaf(kv.z, qv.z, acc[c4 * 4 + 2]);
        acc[c4 * 4 + 3] = fmaf(kv.w, qv.w, acc[c4 * 4 + 3]);
        float4 o;
        o.x = acc[c4 * 4 + 0];
        o.y = acc[c4 * 4 + 1];
        o.z = acc[c4 * 4 + 2];
        o.w = acc[c4 * 4 + 3];
        *reinterpret_cast<float4*>(orow + c4 * 4) = o;
    }

    float s4[N_HEADS];
#pragma unroll
    for (int hh = 0; hh < N_HEADS; ++hh) {
        float t = 0.f;
#pragma unroll
        for (int d = 0; d < HEAD_DIM; ++d) t += acc[hh * HEAD_DIM + d];
        t = fminf(fmaxf(t, -5.f), 5.f);
        s4[hh] = __expf(t);
    }
    *reinterpret_cast<float4*>(s_buf + (size_t)p * N_HEADS) =
        make_float4(s4[0], s4[1], s4[2], s4[3]);
}

// ---------------------------------------------------------------------------
// Gather: one wave owns one (node, tok); walk CSR incoming edges, no atomics.
// ---------------------------------------------------------------------------
__global__ void __launch_bounds__(256) gather_kernel(
    const float* __restrict__ Vh, const float* __restrict__ s_buf,
    const int* __restrict__ src,
    const int* __restrict__ offs, const int* __restrict__ csr,
    float* __restrict__ h_out, int nunits) {
    const int unit = blockIdx.x * (blockDim.x >> 6) + (threadIdx.x >> 6);
    const int lane = threadIdx.x & 63;
    if (unit >= nunits) return;
    const int node = unit >> 3;
    const int tok = unit & 7;
    const int beg = offs[node];
    const int end = offs[node + 1];
    float acc = 0.f;
    float z = 0.f;
    const int hh = lane >> 4;   // head of this lane
    for (int i = beg; i < end; ++i) {
        const int eid = csr[i];
        const int s_i = src[eid];
        const float sh = s_buf[((size_t)eid * N_TOK + tok) * N_HEADS + hh];
        const float v = Vh[((size_t)s_i * N_TOK + tok) * OUT_DIM + lane];
        acc = fmaf(v, sh, acc);
        z += sh;
    }
    h_out[(size_t)unit * OUT_DIM + lane] = acc / (z + 1e-6f);
}

// ---------------------------------------------------------------------------
extern "C" void kernel_launch(void* const* d_in, const int* in_sizes, int n_in,
                              void* d_out, int out_size, void* d_ws, size_t ws_size,
                              hipStream_t stream) {
    const float* h  = (const float*)d_in[0];
    const float* e  = (const float*)d_in[1];
    const int* src  = (const int*)d_in[2];
    const int* dst  = (const int*)d_in[3];
    const float* Qw = (const float*)d_in[4];
    const float* Qb = (const float*)d_in[5];
    const float* Kw = (const float*)d_in[6];
    const float* Kb = (const float*)d_in[7];
    const float* Vw = (const float*)d_in[8];
    const float* Vb = (const float*)d_in[9];
    const float* Ew = (const float*)d_in[10];
    const float* Eb = (const float*)d_in[11];

    const int n_nodes = in_sizes[0] / (N_TOK * IN_DIM);   // 20000
    const int n_edges = in_sizes[2];                      // 200000
    const int nrows   = n_nodes * N_TOK;                  // 160000 node rows
    const int npairs  = n_edges * N_TOK;                  // 1.6M edge pairs
    const int h_out_elems = n_nodes * N_TOK * OUT_DIM;    // 10.24M

    float* h_out = (float*)d_out;
    float* e_out = (float*)d_out + h_out_elems;

    // workspace layout (floats then ints)
    float* Qh    = (float*)d_ws;
    float* Kh    = Qh + (size_t)nrows * OUT_DIM;
    float* Vh    = Kh + (size_t)nrows * OUT_DIM;
    float* s_buf = Vh + (size_t)nrows * OUT_DIM;
    int*   deg   = (int*)(s_buf + (size_t)npairs * N_HEADS);
    int*   offs  = deg + n_nodes;
    int*   cur   = offs + (n_nodes + 1);
    int*   csr   = cur + n_nodes;

    // 1) CSR build
    zero_kernel<<<(n_nodes + 255) / 256, 256, 0, stream>>>(deg, n_nodes);
    hist_kernel<<<(n_edges + 255) / 256, 256, 0, stream>>>(dst, deg, n_edges);
    scan_kernel<<<1, 1024, 0, stream>>>(deg, offs, cur, n_nodes);
    scatter_kernel<<<(n_edges + 255) / 256, 256, 0, stream>>>(dst, cur, csr, n_edges);

    // 2) node projections (Q pre-scaled by 1/sqrt(HEAD_DIM))
    hproj_kernel<<<(nrows + 255) / 256, 256, 0, stream>>>(
        h, Qw, Qb, Kw, Kb, Vw, Vb, Qh, Kh, Vh, nrows);

    // 3) fused edge kernel: pe + score + e_out + s
    edge_kernel<<<(npairs + 255) / 256, 256, 0, stream>>>(
        e, src, dst, Ew, Eb, Qh, Kh, e_out, s_buf, npairs);

    // 4) gather-side segment reduction (no float atomics)
    gather_kernel<<<(nrows + (256 / 64) - 1) / (256 / 64), 256, 0, stream>>>(
        Vh, s_buf, src, offs, csr, h_out, nrows);
}

// Round 4
// 1116.733 us; speedup vs baseline: 1.4437x; 1.4437x over previous
//
#include <hip/hip_runtime.h>
#include <hip/hip_bf16.h>

#define IN_DIM 64
#define N_TOK 8
#define OUT_DIM 64      // N_HEADS * HEAD_DIM
#define HEAD_DIM 16
#define N_HEADS 4

// ---------------------------------------------------------------------------
// CSR build kernels
// ---------------------------------------------------------------------------
__global__ void zero_kernel(int* p, int n) {
    int i = blockIdx.x * blockDim.x + threadIdx.x;
    if (i < n) p[i] = 0;
}

__global__ void hist_kernel(const int* __restrict__ dst, int* __restrict__ deg, int n) {
    int i = blockIdx.x * blockDim.x + threadIdx.x;
    if (i < n) atomicAdd(&deg[dst[i]], 1);
}

__global__ void scan_kernel(const int* __restrict__ deg, int* __restrict__ offs,
                            int* __restrict__ cur, int n) {
    __shared__ int buf[1024];
    __shared__ int carry;
    const int tid = threadIdx.x;
    if (tid == 0) carry = 0;
    __syncthreads();
    for (int base = 0; base < n; base += 1024) {
        int i = base + tid;
        int v = (i < n) ? deg[i] : 0;
        buf[tid] = v;
        __syncthreads();
        for (int off = 1; off < 1024; off <<= 1) {
            int t = (tid >= off) ? buf[tid - off] : 0;
            __syncthreads();
            buf[tid] += t;
            __syncthreads();
        }
        int incl = buf[tid];
        int excl = incl - v + carry;
        if (i < n) { offs[i] = excl; cur[i] = excl; }
        __syncthreads();
        if (tid == 0) carry += buf[1023];
        __syncthreads();
    }
    if (tid == 0) offs[n] = carry;
}

__global__ void scatter_kernel(const int* __restrict__ dst, int* __restrict__ cur,
                               int* __restrict__ csr, int n) {
    int i = blockIdx.x * blockDim.x + threadIdx.x;
    if (i < n) {
        int pos = atomicAdd(&cur[dst[i]], 1);
        csr[pos] = i;
    }
}

// ---------------------------------------------------------------------------
// 16-wide projection slice from an LDS row tile.
// tile: [64 rows][65 floats] (pad 65 -> read bank = (lane+k)%32, 2-way free).
// W rows are wave-uniform (chunk in SGPR) -> scalar loads.
// ---------------------------------------------------------------------------
__device__ __forceinline__ void proj16_acc(const float* __restrict__ tile, int lane,
                                           const float* __restrict__ wb,
                                           float acc[16]) {
#pragma unroll 8
    for (int k = 0; k < 64; ++k) {
        const float ev = tile[lane * 65 + k];
        const float4 w0 = *reinterpret_cast<const float4*>(wb + k * 64);
        const float4 w1 = *reinterpret_cast<const float4*>(wb + k * 64 + 4);
        const float4 w2 = *reinterpret_cast<const float4*>(wb + k * 64 + 8);
        const float4 w3 = *reinterpret_cast<const float4*>(wb + k * 64 + 12);
        acc[0]  = fmaf(ev, w0.x, acc[0]);
        acc[1]  = fmaf(ev, w0.y, acc[1]);
        acc[2]  = fmaf(ev, w0.z, acc[2]);
        acc[3]  = fmaf(ev, w0.w, acc[3]);
        acc[4]  = fmaf(ev, w1.x, acc[4]);
        acc[5]  = fmaf(ev, w1.y, acc[5]);
        acc[6]  = fmaf(ev, w1.z, acc[6]);
        acc[7]  = fmaf(ev, w1.w, acc[7]);
        acc[8]  = fmaf(ev, w2.x, acc[8]);
        acc[9]  = fmaf(ev, w2.y, acc[9]);
        acc[10] = fmaf(ev, w2.z, acc[10]);
        acc[11] = fmaf(ev, w2.w, acc[11]);
        acc[12] = fmaf(ev, w3.x, acc[12]);
        acc[13] = fmaf(ev, w3.y, acc[13]);
        acc[14] = fmaf(ev, w3.z, acc[14]);
        acc[15] = fmaf(ev, w3.w, acc[15]);
    }
}

__device__ __forceinline__ void init16_bias(const float* __restrict__ bb, float acc[16]) {
    const float4 b0 = *reinterpret_cast<const float4*>(bb);
    const float4 b1 = *reinterpret_cast<const float4*>(bb + 4);
    const float4 b2 = *reinterpret_cast<const float4*>(bb + 8);
    const float4 b3 = *reinterpret_cast<const float4*>(bb + 12);
    acc[0] = b0.x;  acc[1] = b0.y;  acc[2] = b0.z;  acc[3] = b0.w;
    acc[4] = b1.x;  acc[5] = b1.y;  acc[6] = b1.z;  acc[7] = b1.w;
    acc[8] = b2.x;  acc[9] = b2.y;  acc[10] = b2.z; acc[11] = b2.w;
    acc[12] = b3.x; acc[13] = b3.y; acc[14] = b3.z; acc[15] = b3.w;
}

__device__ __forceinline__ void store16(float* __restrict__ out, const float acc[16],
                                        float scale) {
    *reinterpret_cast<float4*>(out)      = make_float4(acc[0] * scale, acc[1] * scale,
                                                       acc[2] * scale, acc[3] * scale);
    *reinterpret_cast<float4*>(out + 4)  = make_float4(acc[4] * scale, acc[5] * scale,
                                                       acc[6] * scale, acc[7] * scale);
    *reinterpret_cast<float4*>(out + 8)  = make_float4(acc[8] * scale, acc[9] * scale,
                                                       acc[10] * scale, acc[11] * scale);
    *reinterpret_cast<float4*>(out + 12) = make_float4(acc[12] * scale, acc[13] * scale,
                                                       acc[14] * scale, acc[15] * scale);
}

// ---------------------------------------------------------------------------
// Node projections: 4 waves share a 64-row LDS tile; wave w owns dims [16w,16w+16)
// ---------------------------------------------------------------------------
__global__ void __launch_bounds__(256) hproj_kernel(
    const float* __restrict__ h,
    const float* __restrict__ Qw, const float* __restrict__ Qb,
    const float* __restrict__ Kw, const float* __restrict__ Kb,
    const float* __restrict__ Vw, const float* __restrict__ Vb,
    float* __restrict__ Qh, float* __restrict__ Kh, float* __restrict__ Vh,
    int nrows) {
    __shared__ float tile[64 * 65];
    const int t = threadIdx.x;
    const int lane = t & 63;
    const int chunk = __builtin_amdgcn_readfirstlane(t >> 6);
    const int row0 = blockIdx.x * 64;
    if (row0 >= nrows) return;

#pragma unroll
    for (int i = 0; i < 4; ++i) {
        const int f = i * 1024 + t * 4;
        const float4 v = *reinterpret_cast<const float4*>(h + (size_t)row0 * 64 + f);
        const int r = f >> 6, c = f & 63;
        tile[r * 65 + c + 0] = v.x;
        tile[r * 65 + c + 1] = v.y;
        tile[r * 65 + c + 2] = v.z;
        tile[r * 65 + c + 3] = v.w;
    }
    __syncthreads();

    const int row = row0 + lane;
    const size_t obase = (size_t)row * OUT_DIM + chunk * 16;

    {
        float acc[16];
        init16_bias(Qb + chunk * 16, acc);
        proj16_acc(tile, lane, Qw + chunk * 16, acc);
        store16(Qh + obase, acc, 0.25f);     // fold 1/sqrt(HEAD_DIM)
    }
    {
        float acc[16];
        init16_bias(Kb + chunk * 16, acc);
        proj16_acc(tile, lane, Kw + chunk * 16, acc);
        store16(Kh + obase, acc, 1.0f);
    }
    {
        float acc[16];
        init16_bias(Vb + chunk * 16, acc);
        proj16_acc(tile, lane, Vw + chunk * 16, acc);
        store16(Vh + obase, acc, 1.0f);
    }
}

// ---------------------------------------------------------------------------
// Fused edge kernel: 4 waves share a 64-pair LDS e-tile; wave w owns head w.
// chunk == head, so the clamped score-sum is thread-local (no cross-lane).
// ---------------------------------------------------------------------------
__global__ void __launch_bounds__(256) edge_kernel(
    const float* __restrict__ e,
    const int* __restrict__ src, const int* __restrict__ dst,
    const float* __restrict__ Ew, const float* __restrict__ Eb,
    const float* __restrict__ Qh, const float* __restrict__ Kh,
    float* __restrict__ e_out, float* __restrict__ s_buf,
    int npairs) {
    __shared__ float tile[64 * 65];
    const int t = threadIdx.x;
    const int lane = t & 63;
    const int chunk = __builtin_amdgcn_readfirstlane(t >> 6);
    const int p0 = blockIdx.x * 64;
    if (p0 >= npairs) return;

#pragma unroll
    for (int i = 0; i < 4; ++i) {
        const int f = i * 1024 + t * 4;
        const float4 v = *reinterpret_cast<const float4*>(e + (size_t)p0 * 64 + f);
        const int r = f >> 6, c = f & 63;
        tile[r * 65 + c + 0] = v.x;
        tile[r * 65 + c + 1] = v.y;
        tile[r * 65 + c + 2] = v.z;
        tile[r * 65 + c + 3] = v.w;
    }

    // issue K/Q gathers before the barrier (hide latency under staging)
    const int p = p0 + lane;
    const int eidx = p >> 3;
    const int tok = p & 7;
    const int si = src[eidx];
    const int di = dst[eidx];
    const float* krow = Kh + ((size_t)si * N_TOK + tok) * OUT_DIM + chunk * 16;
    const float* qrow = Qh + ((size_t)di * N_TOK + tok) * OUT_DIM + chunk * 16;
    const float4 kv0 = *reinterpret_cast<const float4*>(krow);
    const float4 kv1 = *reinterpret_cast<const float4*>(krow + 4);
    const float4 kv2 = *reinterpret_cast<const float4*>(krow + 8);
    const float4 kv3 = *reinterpret_cast<const float4*>(krow + 12);
    const float4 qv0 = *reinterpret_cast<const float4*>(qrow);
    const float4 qv1 = *reinterpret_cast<const float4*>(qrow + 4);
    const float4 qv2 = *reinterpret_cast<const float4*>(qrow + 8);
    const float4 qv3 = *reinterpret_cast<const float4*>(qrow + 12);

    __syncthreads();

    float acc[16];
    init16_bias(Eb + chunk * 16, acc);
    proj16_acc(tile, lane, Ew + chunk * 16, acc);

    acc[0]  = fmaf(kv0.x, qv0.x, acc[0]);
    acc[1]  = fmaf(kv0.y, qv0.y, acc[1]);
    acc[2]  = fmaf(kv0.z, qv0.z, acc[2]);
    acc[3]  = fmaf(kv0.w, qv0.w, acc[3]);
    acc[4]  = fmaf(kv1.x, qv1.x, acc[4]);
    acc[5]  = fmaf(kv1.y, qv1.y, acc[5]);
    acc[6]  = fmaf(kv1.z, qv1.z, acc[6]);
    acc[7]  = fmaf(kv1.w, qv1.w, acc[7]);
    acc[8]  = fmaf(kv2.x, qv2.x, acc[8]);
    acc[9]  = fmaf(kv2.y, qv2.y, acc[9]);
    acc[10] = fmaf(kv2.z, qv2.z, acc[10]);
    acc[11] = fmaf(kv2.w, qv2.w, acc[11]);
    acc[12] = fmaf(kv3.x, qv3.x, acc[12]);
    acc[13] = fmaf(kv3.y, qv3.y, acc[13]);
    acc[14] = fmaf(kv3.z, qv3.z, acc[14]);
    acc[15] = fmaf(kv3.w, qv3.w, acc[15]);

    float* orow = e_out + (size_t)p * OUT_DIM + chunk * 16;
    *reinterpret_cast<float4*>(orow)      = make_float4(acc[0], acc[1], acc[2], acc[3]);
    *reinterpret_cast<float4*>(orow + 4)  = make_float4(acc[4], acc[5], acc[6], acc[7]);
    *reinterpret_cast<float4*>(orow + 8)  = make_float4(acc[8], acc[9], acc[10], acc[11]);
    *reinterpret_cast<float4*>(orow + 12) = make_float4(acc[12], acc[13], acc[14], acc[15]);

    float s01 = (acc[0] + acc[1]) + (acc[2] + acc[3]);
    float s23 = (acc[4] + acc[5]) + (acc[6] + acc[7]);
    float s45 = (acc[8] + acc[9]) + (acc[10] + acc[11]);
    float s67 = (acc[12] + acc[13]) + (acc[14] + acc[15]);
    float ssum = (s01 + s23) + (s45 + s67);
    ssum = fminf(fmaxf(ssum, -5.f), 5.f);
    s_buf[(size_t)p * N_HEADS + chunk] = __expf(ssum);
}

// ---------------------------------------------------------------------------
// Gather: wave per (node, tok); lane-parallel csr/src preload + shfl broadcast.
// ---------------------------------------------------------------------------
__global__ void __launch_bounds__(256) gather_kernel(
    const float* __restrict__ Vh, const float* __restrict__ s_buf,
    const int* __restrict__ src,
    const int* __restrict__ offs, const int* __restrict__ csr,
    float* __restrict__ h_out, int nunits) {
    const int unit = blockIdx.x * 4 + (threadIdx.x >> 6);
    const int lane = threadIdx.x & 63;
    if (unit >= nunits) return;
    const int node = unit >> 3;
    const int tok = unit & 7;
    const int beg = offs[node];
    const int end = offs[node + 1];
    const int hh = lane >> 4;
    float acc = 0.f;
    float z = 0.f;
    for (int base = beg; base < end; base += 64) {
        const int n = min(64, end - base);
        int eid = 0, sidx = 0;
        if (lane < n) {
            eid = csr[base + lane];      // coalesced
            sidx = src[eid];             // lane-parallel random
        }
        for (int j = 0; j < n; ++j) {
            const int ej = __shfl(eid, j);
            const int sj = __shfl(sidx, j);
            const float sh = s_buf[((size_t)ej * N_TOK + tok) * N_HEADS + hh];
            const float v = Vh[((size_t)sj * N_TOK + tok) * OUT_DIM + lane];
            acc = fmaf(v, sh, acc);
            z += sh;
        }
    }
    h_out[(size_t)unit * OUT_DIM + lane] = acc / (z + 1e-6f);
}

// ---------------------------------------------------------------------------
extern "C" void kernel_launch(void* const* d_in, const int* in_sizes, int n_in,
                              void* d_out, int out_size, void* d_ws, size_t ws_size,
                              hipStream_t stream) {
    const float* h  = (const float*)d_in[0];
    const float* e  = (const float*)d_in[1];
    const int* src  = (const int*)d_in[2];
    const int* dst  = (const int*)d_in[3];
    const float* Qw = (const float*)d_in[4];
    const float* Qb = (const float*)d_in[5];
    const float* Kw = (const float*)d_in[6];
    const float* Kb = (const float*)d_in[7];
    const float* Vw = (const float*)d_in[8];
    const float* Vb = (const float*)d_in[9];
    const float* Ew = (const float*)d_in[10];
    const float* Eb = (const float*)d_in[11];

    const int n_nodes = in_sizes[0] / (N_TOK * IN_DIM);   // 20000
    const int n_edges = in_sizes[2];                      // 200000
    const int nrows   = n_nodes * N_TOK;                  // 160000
    const int npairs  = n_edges * N_TOK;                  // 1.6M
    const int h_out_elems = n_nodes * N_TOK * OUT_DIM;

    float* h_out = (float*)d_out;
    float* e_out = (float*)d_out + h_out_elems;

    float* Qh    = (float*)d_ws;
    float* Kh    = Qh + (size_t)nrows * OUT_DIM;
    float* Vh    = Kh + (size_t)nrows * OUT_DIM;
    float* s_buf = Vh + (size_t)nrows * OUT_DIM;
    int*   deg   = (int*)(s_buf + (size_t)npairs * N_HEADS);
    int*   offs  = deg + n_nodes;
    int*   cur   = offs + (n_nodes + 1);
    int*   csr   = cur + n_nodes;

    zero_kernel<<<(n_nodes + 255) / 256, 256, 0, stream>>>(deg, n_nodes);
    hist_kernel<<<(n_edges + 255) / 256, 256, 0, stream>>>(dst, deg, n_edges);
    scan_kernel<<<1, 1024, 0, stream>>>(deg, offs, cur, n_nodes);
    scatter_kernel<<<(n_edges + 255) / 256, 256, 0, stream>>>(dst, cur, csr, n_edges);

    hproj_kernel<<<(nrows + 63) / 64, 256, 0, stream>>>(
        h, Qw, Qb, Kw, Kb, Vw, Vb, Qh, Kh, Vh, nrows);

    edge_kernel<<<(npairs + 63) / 64, 256, 0, stream>>>(
        e, src, dst, Ew, Eb, Qh, Kh, e_out, s_buf, npairs);

    gather_kernel<<<(nrows + 3) / 4, 256, 0, stream>>>(
        Vh, s_buf, src, offs, csr, h_out, nrows);
}

// Round 7
// 990.438 us; speedup vs baseline: 1.6278x; 1.1275x over previous
//
#include <hip/hip_runtime.h>
#include <hip/hip_bf16.h>

#define IN_DIM 64
#define N_TOK 8
#define OUT_DIM 64      // N_HEADS * HEAD_DIM
#define HEAD_DIM 16
#define N_HEADS 4

// ---------------------------------------------------------------------------
// CSR build kernels
// ---------------------------------------------------------------------------
__global__ void zero_kernel(int* p, int n) {
    int i = blockIdx.x * blockDim.x + threadIdx.x;
    if (i < n) p[i] = 0;
}

__global__ void hist_kernel(const int* __restrict__ dst, int* __restrict__ deg, int n) {
    int i = blockIdx.x * blockDim.x + threadIdx.x;
    if (i < n) atomicAdd(&deg[dst[i]], 1);
}

// single-block exclusive scan, shfl-based: 4 barriers/chunk instead of ~20
__global__ void scan_kernel(const int* __restrict__ deg, int* __restrict__ offs,
                            int* __restrict__ cur, int n) {
    __shared__ int wsum[17];
    __shared__ int carry;
    const int tid = threadIdx.x;           // 1024 threads = 16 waves
    const int lane = tid & 63;
    const int wid = tid >> 6;
    if (tid == 0) carry = 0;
    __syncthreads();
    for (int base = 0; base < n; base += 1024) {
        const int i = base + tid;
        const int v = (i < n) ? deg[i] : 0;
        int x = v;                          // wave-inclusive scan
#pragma unroll
        for (int d = 1; d < 64; d <<= 1) {
            int y = __shfl_up(x, d);
            if (lane >= d) x += y;
        }
        if (lane == 63) wsum[wid] = x;
        __syncthreads();
        if (wid == 0 && lane < 16) {        // scan the 16 wave sums
            const int a = wsum[lane];
            int s = a;
#pragma unroll
            for (int d = 1; d < 16; d <<= 1) {
                int y = __shfl_up(s, d);
                if (lane >= d) s += y;
            }
            wsum[lane] = s - a;             // exclusive wave offset
            if (lane == 15) wsum[16] = s;   // chunk total
        }
        __syncthreads();
        const int excl = x - v + wsum[wid] + carry;
        if (i < n) { offs[i] = excl; cur[i] = excl; }
        __syncthreads();
        if (tid == 0) carry += wsum[16];
        __syncthreads();
    }
    if (tid == 0) offs[n] = carry;
}

__global__ void scatter_kernel(const int* __restrict__ dst, int* __restrict__ cur,
                               int* __restrict__ csr, int n) {
    int i = blockIdx.x * blockDim.x + threadIdx.x;
    if (i < n) {
        int pos = atomicAdd(&cur[dst[i]], 1);
        csr[pos] = i;
    }
}

// ---------------------------------------------------------------------------
// 16-wide projection slice from an LDS row tile (stride 65: bank-free scalar
// reads). W rows wave-uniform (chunk in SGPR) -> scalar loads.
// ---------------------------------------------------------------------------
__device__ __forceinline__ void proj16_acc(const float* __restrict__ tile, int lane,
                                           const float* __restrict__ wb,
                                           float acc[16]) {
#pragma unroll 8
    for (int k = 0; k < 64; ++k) {
        const float ev = tile[lane * 65 + k];
        const float4 w0 = *reinterpret_cast<const float4*>(wb + k * 64);
        const float4 w1 = *reinterpret_cast<const float4*>(wb + k * 64 + 4);
        const float4 w2 = *reinterpret_cast<const float4*>(wb + k * 64 + 8);
        const float4 w3 = *reinterpret_cast<const float4*>(wb + k * 64 + 12);
        acc[0]  = fmaf(ev, w0.x, acc[0]);
        acc[1]  = fmaf(ev, w0.y, acc[1]);
        acc[2]  = fmaf(ev, w0.z, acc[2]);
        acc[3]  = fmaf(ev, w0.w, acc[3]);
        acc[4]  = fmaf(ev, w1.x, acc[4]);
        acc[5]  = fmaf(ev, w1.y, acc[5]);
        acc[6]  = fmaf(ev, w1.z, acc[6]);
        acc[7]  = fmaf(ev, w1.w, acc[7]);
        acc[8]  = fmaf(ev, w2.x, acc[8]);
        acc[9]  = fmaf(ev, w2.y, acc[9]);
        acc[10] = fmaf(ev, w2.z, acc[10]);
        acc[11] = fmaf(ev, w2.w, acc[11]);
        acc[12] = fmaf(ev, w3.x, acc[12]);
        acc[13] = fmaf(ev, w3.y, acc[13]);
        acc[14] = fmaf(ev, w3.z, acc[14]);
        acc[15] = fmaf(ev, w3.w, acc[15]);
    }
}

__device__ __forceinline__ void init16_bias(const float* __restrict__ bb, float acc[16]) {
    const float4 b0 = *reinterpret_cast<const float4*>(bb);
    const float4 b1 = *reinterpret_cast<const float4*>(bb + 4);
    const float4 b2 = *reinterpret_cast<const float4*>(bb + 8);
    const float4 b3 = *reinterpret_cast<const float4*>(bb + 12);
    acc[0] = b0.x;  acc[1] = b0.y;  acc[2] = b0.z;  acc[3] = b0.w;
    acc[4] = b1.x;  acc[5] = b1.y;  acc[6] = b1.z;  acc[7] = b1.w;
    acc[8] = b2.x;  acc[9] = b2.y;  acc[10] = b2.z; acc[11] = b2.w;
    acc[12] = b3.x; acc[13] = b3.y; acc[14] = b3.z; acc[15] = b3.w;
}

// ---------------------------------------------------------------------------
// Node projections: stage h-tile; compute Q/K/V accs; transpose each output
// through the tile so every global store is a coalesced float4 stream.
// ---------------------------------------------------------------------------
__global__ void __launch_bounds__(256) hproj_kernel(
    const float* __restrict__ h,
    const float* __restrict__ Qw, const float* __restrict__ Qb,
    const float* __restrict__ Kw, const float* __restrict__ Kb,
    const float* __restrict__ Vw, const float* __restrict__ Vb,
    float* __restrict__ Qh, float* __restrict__ Kh, float* __restrict__ Vh,
    int nrows) {
    __shared__ float tile[64 * 65];
    const int t = threadIdx.x;
    const int lane = t & 63;
    const int chunk = __builtin_amdgcn_readfirstlane(t >> 6);
    const int row0 = blockIdx.x * 64;
    if (row0 >= nrows) return;

#pragma unroll
    for (int i = 0; i < 4; ++i) {
        const int f = i * 1024 + t * 4;
        const float4 v = *reinterpret_cast<const float4*>(h + (size_t)row0 * 64 + f);
        const int r = f >> 6, c = f & 63;
        tile[r * 65 + c + 0] = v.x;
        tile[r * 65 + c + 1] = v.y;
        tile[r * 65 + c + 2] = v.z;
        tile[r * 65 + c + 3] = v.w;
    }
    __syncthreads();

    float aq[16], ak[16], av[16];
    init16_bias(Qb + chunk * 16, aq);
    proj16_acc(tile, lane, Qw + chunk * 16, aq);
    init16_bias(Kb + chunk * 16, ak);
    proj16_acc(tile, lane, Kw + chunk * 16, ak);
    init16_bias(Vb + chunk * 16, av);
    proj16_acc(tile, lane, Vw + chunk * 16, av);

    // Q (fold 1/sqrt(HEAD_DIM)=0.25), then K, then V: stage -> coalesced store
    __syncthreads();
#pragma unroll
    for (int j = 0; j < 16; ++j) tile[lane * 65 + chunk * 16 + j] = aq[j] * 0.25f;
    __syncthreads();
#pragma unroll
    for (int i = 0; i < 4; ++i) {
        const int f = i * 1024 + t * 4;
        const int r = f >> 6, c = f & 63;
        *reinterpret_cast<float4*>(Qh + (size_t)row0 * 64 + f) =
            make_float4(tile[r * 65 + c], tile[r * 65 + c + 1],
                        tile[r * 65 + c + 2], tile[r * 65 + c + 3]);
    }
    __syncthreads();
#pragma unroll
    for (int j = 0; j < 16; ++j) tile[lane * 65 + chunk * 16 + j] = ak[j];
    __syncthreads();
#pragma unroll
    for (int i = 0; i < 4; ++i) {
        const int f = i * 1024 + t * 4;
        const int r = f >> 6, c = f & 63;
        *reinterpret_cast<float4*>(Kh + (size_t)row0 * 64 + f) =
            make_float4(tile[r * 65 + c], tile[r * 65 + c + 1],
                        tile[r * 65 + c + 2], tile[r * 65 + c + 3]);
    }
    __syncthreads();
#pragma unroll
    for (int j = 0; j < 16; ++j) tile[lane * 65 + chunk * 16 + j] = av[j];
    __syncthreads();
#pragma unroll
    for (int i = 0; i < 4; ++i) {
        const int f = i * 1024 + t * 4;
        const int r = f >> 6, c = f & 63;
        *reinterpret_cast<float4*>(Vh + (size_t)row0 * 64 + f) =
            make_float4(tile[r * 65 + c], tile[r * 65 + c + 1],
                        tile[r * 65 + c + 2], tile[r * 65 + c + 3]);
    }
}

// ---------------------------------------------------------------------------
// Fused edge kernel v3: 64 pairs = 8 edges per block.
//  - stage e-tile (64x65) coalesced
//  - stage K-rows (src) and Q-rows (dst) cooperatively: 8 x 2KB contiguous
//    regions each -> LDS stride-68 (16B-aligned, bank-balanced b128)
//  - compute pe + K*Q entirely from LDS
//  - transpose e_out through e-tile -> coalesced float4 stores
//  - s_buf laid out [head][pair] -> coalesced wave writes
// ---------------------------------------------------------------------------
__global__ void __launch_bounds__(256) edge_kernel(
    const float* __restrict__ e,
    const int* __restrict__ src, const int* __restrict__ dst,
    const float* __restrict__ Ew, const float* __restrict__ Eb,
    const float* __restrict__ Qh, const float* __restrict__ Kh,
    float* __restrict__ e_out, float* __restrict__ s_buf,
    int npairs, int n_edges) {
    __shared__ float et[64 * 65];
    __shared__ float kt[64 * 68];
    __shared__ float qt[64 * 68];
    const int t = threadIdx.x;
    const int lane = t & 63;
    const int chunk = __builtin_amdgcn_readfirstlane(t >> 6);   // head, SGPR
    const int p0 = blockIdx.x * 64;
    const int e0 = p0 >> 3;
    if (p0 >= npairs) return;

    // stage e-tile (stride 65; scalar writes are bank-balanced)
#pragma unroll
    for (int i = 0; i < 4; ++i) {
        const int f = i * 1024 + t * 4;
        const float4 v = *reinterpret_cast<const float4*>(e + (size_t)p0 * 64 + f);
        const int r = f >> 6, c = f & 63;
        et[r * 65 + c + 0] = v.x;
        et[r * 65 + c + 1] = v.y;
        et[r * 65 + c + 2] = v.z;
        et[r * 65 + c + 3] = v.w;
    }

    // stage K (src rows) and Q (dst rows): 8 edges x 512 floats, contiguous
    float4* kt4 = reinterpret_cast<float4*>(kt);
    float4* qt4 = reinterpret_cast<float4*>(qt);
#pragma unroll
    for (int i = 0; i < 4; ++i) {
        const int f = i * 1024 + t * 4;
        int ee = e0 + (f >> 9);
        if (ee >= n_edges) ee = n_edges - 1;
        const int o = f & 511;
        const int se = src[ee];
        const int de = dst[ee];
        const float4 kv = *reinterpret_cast<const float4*>(Kh + (size_t)se * 512 + o);
        const float4 qv = *reinterpret_cast<const float4*>(Qh + (size_t)de * 512 + o);
        const int r = f >> 6, c4 = (f & 63) >> 2;
        kt4[r * 17 + c4] = kv;
        qt4[r * 17 + c4] = qv;
    }
    __syncthreads();

    float acc[16];
    init16_bias(Eb + chunk * 16, acc);
    proj16_acc(et, lane, Ew + chunk * 16, acc);

    // score += K[src]*Q_scaled[dst] for this head's 16 dims (LDS b128 reads)
#pragma unroll
    for (int c4 = 0; c4 < 4; ++c4) {
        const float4 kv = kt4[lane * 17 + chunk * 4 + c4];
        const float4 qv = qt4[lane * 17 + chunk * 4 + c4];
        acc[c4 * 4 + 0] = fmaf(kv.x, qv.x, acc[c4 * 4 + 0]);
        acc[c4 * 4 + 1] = fmaf(kv.y, qv.y, acc[c4 * 4 + 1]);
        acc[c4 * 4 + 2] = fmaf(kv.z, qv.z, acc[c4 * 4 + 2]);
        acc[c4 * 4 + 3] = fmaf(kv.w, qv.w, acc[c4 * 4 + 3]);
    }

    // s = exp(clip(head sum)); s_buf layout [head][pair] -> coalesced write
    {
        float s01 = (acc[0] + acc[1]) + (acc[2] + acc[3]);
        float s23 = (acc[4] + acc[5]) + (acc[6] + acc[7]);
        float s45 = (acc[8] + acc[9]) + (acc[10] + acc[11]);
        float s67 = (acc[12] + acc[13]) + (acc[14] + acc[15]);
        float ssum = (s01 + s23) + (s45 + s67);
        ssum = fminf(fmaxf(ssum, -5.f), 5.f);
        s_buf[(size_t)chunk * npairs + p0 + lane] = __expf(ssum);
    }

    // transpose e_out through et -> coalesced stores
    __syncthreads();     // all waves done reading et/kt/qt
#pragma unroll
    for (int j = 0; j < 16; ++j) et[lane * 65 + chunk * 16 + j] = acc[j];
    __syncthreads();
#pragma unroll
    for (int i = 0; i < 4; ++i) {
        const int f = i * 1024 + t * 4;
        const int r = f >> 6, c = f & 63;
        *reinterpret_cast<float4*>(e_out + (size_t)p0 * 64 + f) =
            make_float4(et[r * 65 + c], et[r * 65 + c + 1],
                        et[r * 65 + c + 2], et[r * 65 + c + 3]);
    }
}

// ---------------------------------------------------------------------------
// Gather: wave per (node, tok); lane-parallel csr/src preload + shfl broadcast,
// 2x unrolled for load ILP. s_buf layout [head][pair].
// ---------------------------------------------------------------------------
__global__ void __launch_bounds__(256) gather_kernel(
    const float* __restrict__ Vh, const float* __restrict__ s_buf,
    const int* __restrict__ src,
    const int* __restrict__ offs, const int* __restrict__ csr,
    float* __restrict__ h_out, int nunits, int npairs) {
    const int unit = blockIdx.x * 4 + (threadIdx.x >> 6);
    const int lane = threadIdx.x & 63;
    if (unit >= nunits) return;
    const int node = unit >> 3;
    const int tok = unit & 7;
    const int beg = offs[node];
    const int end = offs[node + 1];
    const int hh = lane >> 4;
    const float* sb = s_buf + (size_t)hh * npairs + tok;
    float acc = 0.f;
    float z = 0.f;
    for (int base = beg; base < end; base += 64) {
        const int nn = min(64, end - base);
        int eid = 0, sidx = 0;
        if (lane < nn) {
            eid = csr[base + lane];      // coalesced
            sidx = src[eid];             // lane-parallel random
        }
        int j = 0;
        for (; j + 1 < nn; j += 2) {
            const int ej0 = __shfl(eid, j),     ej1 = __shfl(eid, j + 1);
            const int sj0 = __shfl(sidx, j),    sj1 = __shfl(sidx, j + 1);
            const float sh0 = sb[(size_t)ej0 * 8];
            const float sh1 = sb[(size_t)ej1 * 8];
            const float v0 = Vh[((size_t)sj0 * 8 + tok) * 64 + lane];
            const float v1 = Vh[((size_t)sj1 * 8 + tok) * 64 + lane];
            acc = fmaf(v0, sh0, acc); z += sh0;
            acc = fmaf(v1, sh1, acc); z += sh1;
        }
        if (j < nn) {
            const int ej = __shfl(eid, j);
            const int sj = __shfl(sidx, j);
            const float sh = sb[(size_t)ej * 8];
            const float v = Vh[((size_t)sj * 8 + tok) * 64 + lane];
            acc = fmaf(v, sh, acc); z += sh;
        }
    }
    h_out[(size_t)unit * OUT_DIM + lane] = acc / (z + 1e-6f);
}

// ---------------------------------------------------------------------------
extern "C" void kernel_launch(void* const* d_in, const int* in_sizes, int n_in,
                              void* d_out, int out_size, void* d_ws, size_t ws_size,
                              hipStream_t stream) {
    const float* h  = (const float*)d_in[0];
    const float* e  = (const float*)d_in[1];
    const int* src  = (const int*)d_in[2];
    const int* dst  = (const int*)d_in[3];
    const float* Qw = (const float*)d_in[4];
    const float* Qb = (const float*)d_in[5];
    const float* Kw = (const float*)d_in[6];
    const float* Kb = (const float*)d_in[7];
    const float* Vw = (const float*)d_in[8];
    const float* Vb = (const float*)d_in[9];
    const float* Ew = (const float*)d_in[10];
    const float* Eb = (const float*)d_in[11];

    const int n_nodes = in_sizes[0] / (N_TOK * IN_DIM);   // 20000
    const int n_edges = in_sizes[2];                      // 200000
    const int nrows   = n_nodes * N_TOK;                  // 160000
    const int npairs  = n_edges * N_TOK;                  // 1.6M
    const int h_out_elems = n_nodes * N_TOK * OUT_DIM;

    float* h_out = (float*)d_out;
    float* e_out = (float*)d_out + h_out_elems;

    float* Qh    = (float*)d_ws;
    float* Kh    = Qh + (size_t)nrows * OUT_DIM;
    float* Vh    = Kh + (size_t)nrows * OUT_DIM;
    float* s_buf = Vh + (size_t)nrows * OUT_DIM;          // [N_HEADS][npairs]
    int*   deg   = (int*)(s_buf + (size_t)npairs * N_HEADS);
    int*   offs  = deg + n_nodes;
    int*   cur   = offs + (n_nodes + 1);
    int*   csr   = cur + n_nodes;

    zero_kernel<<<(n_nodes + 255) / 256, 256, 0, stream>>>(deg, n_nodes);
    hist_kernel<<<(n_edges + 255) / 256, 256, 0, stream>>>(dst, deg, n_edges);
    scan_kernel<<<1, 1024, 0, stream>>>(deg, offs, cur, n_nodes);
    scatter_kernel<<<(n_edges + 255) / 256, 256, 0, stream>>>(dst, cur, csr, n_edges);

    hproj_kernel<<<(nrows + 63) / 64, 256, 0, stream>>>(
        h, Qw, Qb, Kw, Kb, Vw, Vb, Qh, Kh, Vh, nrows);

    edge_kernel<<<(npairs + 63) / 64, 256, 0, stream>>>(
        e, src, dst, Ew, Eb, Qh, Kh, e_out, s_buf, npairs, n_edges);

    gather_kernel<<<(nrows + 3) / 4, 256, 0, stream>>>(
        Vh, s_buf, src, offs, csr, h_out, nrows, npairs);
}

// Round 8
// 954.343 us; speedup vs baseline: 1.6893x; 1.0378x over previous
//
#include <hip/hip_runtime.h>
#include <hip/hip_bf16.h>

#define IN_DIM 64
#define N_TOK 8
#define OUT_DIM 64      // N_HEADS * HEAD_DIM
#define HEAD_DIM 16
#define N_HEADS 4

// ---------------------------------------------------------------------------
// CSR build kernels
// ---------------------------------------------------------------------------
__global__ void zero_kernel(int* p, int n) {
    int i = blockIdx.x * blockDim.x + threadIdx.x;
    if (i < n) p[i] = 0;
}

__global__ void hist_kernel(const int* __restrict__ dst, int* __restrict__ deg, int n) {
    int i = blockIdx.x * blockDim.x + threadIdx.x;
    if (i < n) atomicAdd(&deg[dst[i]], 1);
}

// single-block exclusive scan, shfl-based: 4 barriers/chunk instead of ~20
__global__ void scan_kernel(const int* __restrict__ deg, int* __restrict__ offs,
                            int* __restrict__ cur, int n) {
    __shared__ int wsum[17];
    __shared__ int carry;
    const int tid = threadIdx.x;           // 1024 threads = 16 waves
    const int lane = tid & 63;
    const int wid = tid >> 6;
    if (tid == 0) carry = 0;
    __syncthreads();
    for (int base = 0; base < n; base += 1024) {
        const int i = base + tid;
        const int v = (i < n) ? deg[i] : 0;
        int x = v;                          // wave-inclusive scan
#pragma unroll
        for (int d = 1; d < 64; d <<= 1) {
            int y = __shfl_up(x, d);
            if (lane >= d) x += y;
        }
        if (lane == 63) wsum[wid] = x;
        __syncthreads();
        if (wid == 0 && lane < 16) {        // scan the 16 wave sums
            const int a = wsum[lane];
            int s = a;
#pragma unroll
            for (int d = 1; d < 16; d <<= 1) {
                int y = __shfl_up(s, d);
                if (lane >= d) s += y;
            }
            wsum[lane] = s - a;             // exclusive wave offset
            if (lane == 15) wsum[16] = s;   // chunk total
        }
        __syncthreads();
        const int excl = x - v + wsum[wid] + carry;
        if (i < n) { offs[i] = excl; cur[i] = excl; }
        __syncthreads();
        if (tid == 0) carry += wsum[16];
        __syncthreads();
    }
    if (tid == 0) offs[n] = carry;
}

__global__ void scatter_kernel(const int* __restrict__ dst, int* __restrict__ cur,
                               int* __restrict__ csr, int n) {
    int i = blockIdx.x * blockDim.x + threadIdx.x;
    if (i < n) {
        int pos = atomicAdd(&cur[dst[i]], 1);
        csr[pos] = i;
    }
}

// ---------------------------------------------------------------------------
// 16-wide projection slice from an LDS row tile (stride 65: bank-free scalar
// reads). W rows wave-uniform (chunk in SGPR) -> scalar loads.
// ---------------------------------------------------------------------------
__device__ __forceinline__ void proj16_acc(const float* __restrict__ tile, int lane,
                                           const float* __restrict__ wb,
                                           float acc[16]) {
#pragma unroll 8
    for (int k = 0; k < 64; ++k) {
        const float ev = tile[lane * 65 + k];
        const float4 w0 = *reinterpret_cast<const float4*>(wb + k * 64);
        const float4 w1 = *reinterpret_cast<const float4*>(wb + k * 64 + 4);
        const float4 w2 = *reinterpret_cast<const float4*>(wb + k * 64 + 8);
        const float4 w3 = *reinterpret_cast<const float4*>(wb + k * 64 + 12);
        acc[0]  = fmaf(ev, w0.x, acc[0]);
        acc[1]  = fmaf(ev, w0.y, acc[1]);
        acc[2]  = fmaf(ev, w0.z, acc[2]);
        acc[3]  = fmaf(ev, w0.w, acc[3]);
        acc[4]  = fmaf(ev, w1.x, acc[4]);
        acc[5]  = fmaf(ev, w1.y, acc[5]);
        acc[6]  = fmaf(ev, w1.z, acc[6]);
        acc[7]  = fmaf(ev, w1.w, acc[7]);
        acc[8]  = fmaf(ev, w2.x, acc[8]);
        acc[9]  = fmaf(ev, w2.y, acc[9]);
        acc[10] = fmaf(ev, w2.z, acc[10]);
        acc[11] = fmaf(ev, w2.w, acc[11]);
        acc[12] = fmaf(ev, w3.x, acc[12]);
        acc[13] = fmaf(ev, w3.y, acc[13]);
        acc[14] = fmaf(ev, w3.z, acc[14]);
        acc[15] = fmaf(ev, w3.w, acc[15]);
    }
}

__device__ __forceinline__ void init16_bias(const float* __restrict__ bb, float acc[16]) {
    const float4 b0 = *reinterpret_cast<const float4*>(bb);
    const float4 b1 = *reinterpret_cast<const float4*>(bb + 4);
    const float4 b2 = *reinterpret_cast<const float4*>(bb + 8);
    const float4 b3 = *reinterpret_cast<const float4*>(bb + 12);
    acc[0] = b0.x;  acc[1] = b0.y;  acc[2] = b0.z;  acc[3] = b0.w;
    acc[4] = b1.x;  acc[5] = b1.y;  acc[6] = b1.z;  acc[7] = b1.w;
    acc[8] = b2.x;  acc[9] = b2.y;  acc[10] = b2.z; acc[11] = b2.w;
    acc[12] = b3.x; acc[13] = b3.y; acc[14] = b3.z; acc[15] = b3.w;
}

// ---------------------------------------------------------------------------
// Node projections: stage h-tile; compute Q/K/V accs; transpose each output
// through the tile so every global store is a coalesced float4 stream.
// ---------------------------------------------------------------------------
__global__ void __launch_bounds__(256) hproj_kernel(
    const float* __restrict__ h,
    const float* __restrict__ Qw, const float* __restrict__ Qb,
    const float* __restrict__ Kw, const float* __restrict__ Kb,
    const float* __restrict__ Vw, const float* __restrict__ Vb,
    float* __restrict__ Qh, float* __restrict__ Kh, float* __restrict__ Vh,
    int nrows) {
    __shared__ float tile[64 * 65];
    const int t = threadIdx.x;
    const int lane = t & 63;
    const int chunk = __builtin_amdgcn_readfirstlane(t >> 6);
    const int row0 = blockIdx.x * 64;
    if (row0 >= nrows) return;

#pragma unroll
    for (int i = 0; i < 4; ++i) {
        const int f = i * 1024 + t * 4;
        const float4 v = *reinterpret_cast<const float4*>(h + (size_t)row0 * 64 + f);
        const int r = f >> 6, c = f & 63;
        tile[r * 65 + c + 0] = v.x;
        tile[r * 65 + c + 1] = v.y;
        tile[r * 65 + c + 2] = v.z;
        tile[r * 65 + c + 3] = v.w;
    }
    __syncthreads();

    float aq[16], ak[16], av[16];
    init16_bias(Qb + chunk * 16, aq);
    proj16_acc(tile, lane, Qw + chunk * 16, aq);
    init16_bias(Kb + chunk * 16, ak);
    proj16_acc(tile, lane, Kw + chunk * 16, ak);
    init16_bias(Vb + chunk * 16, av);
    proj16_acc(tile, lane, Vw + chunk * 16, av);

    // Q (fold 1/sqrt(HEAD_DIM)=0.25), then K, then V: stage -> coalesced store
    __syncthreads();
#pragma unroll
    for (int j = 0; j < 16; ++j) tile[lane * 65 + chunk * 16 + j] = aq[j] * 0.25f;
    __syncthreads();
#pragma unroll
    for (int i = 0; i < 4; ++i) {
        const int f = i * 1024 + t * 4;
        const int r = f >> 6, c = f & 63;
        *reinterpret_cast<float4*>(Qh + (size_t)row0 * 64 + f) =
            make_float4(tile[r * 65 + c], tile[r * 65 + c + 1],
                        tile[r * 65 + c + 2], tile[r * 65 + c + 3]);
    }
    __syncthreads();
#pragma unroll
    for (int j = 0; j < 16; ++j) tile[lane * 65 + chunk * 16 + j] = ak[j];
    __syncthreads();
#pragma unroll
    for (int i = 0; i < 4; ++i) {
        const int f = i * 1024 + t * 4;
        const int r = f >> 6, c = f & 63;
        *reinterpret_cast<float4*>(Kh + (size_t)row0 * 64 + f) =
            make_float4(tile[r * 65 + c], tile[r * 65 + c + 1],
                        tile[r * 65 + c + 2], tile[r * 65 + c + 3]);
    }
    __syncthreads();
#pragma unroll
    for (int j = 0; j < 16; ++j) tile[lane * 65 + chunk * 16 + j] = av[j];
    __syncthreads();
#pragma unroll
    for (int i = 0; i < 4; ++i) {
        const int f = i * 1024 + t * 4;
        const int r = f >> 6, c = f & 63;
        *reinterpret_cast<float4*>(Vh + (size_t)row0 * 64 + f) =
            make_float4(tile[r * 65 + c], tile[r * 65 + c + 1],
                        tile[r * 65 + c + 2], tile[r * 65 + c + 3]);
    }
}

// ---------------------------------------------------------------------------
// Fused edge kernel v3 (unchanged except s_buf layout [pair][head]):
// 64 pairs = 8 edges per block; e-tile + K/Q rows staged in LDS; e_out
// transposed through LDS for coalesced stores.
// ---------------------------------------------------------------------------
__global__ void __launch_bounds__(256) edge_kernel(
    const float* __restrict__ e,
    const int* __restrict__ src, const int* __restrict__ dst,
    const float* __restrict__ Ew, const float* __restrict__ Eb,
    const float* __restrict__ Qh, const float* __restrict__ Kh,
    float* __restrict__ e_out, float* __restrict__ s_buf,
    int npairs, int n_edges) {
    __shared__ float et[64 * 65];
    __shared__ float kt[64 * 68];
    __shared__ float qt[64 * 68];
    const int t = threadIdx.x;
    const int lane = t & 63;
    const int chunk = __builtin_amdgcn_readfirstlane(t >> 6);   // head, SGPR
    const int p0 = blockIdx.x * 64;
    const int e0 = p0 >> 3;
    if (p0 >= npairs) return;

    // stage e-tile (stride 65; scalar writes are bank-balanced)
#pragma unroll
    for (int i = 0; i < 4; ++i) {
        const int f = i * 1024 + t * 4;
        const float4 v = *reinterpret_cast<const float4*>(e + (size_t)p0 * 64 + f);
        const int r = f >> 6, c = f & 63;
        et[r * 65 + c + 0] = v.x;
        et[r * 65 + c + 1] = v.y;
        et[r * 65 + c + 2] = v.z;
        et[r * 65 + c + 3] = v.w;
    }

    // stage K (src rows) and Q (dst rows): 8 edges x 512 floats, contiguous
    float4* kt4 = reinterpret_cast<float4*>(kt);
    float4* qt4 = reinterpret_cast<float4*>(qt);
#pragma unroll
    for (int i = 0; i < 4; ++i) {
        const int f = i * 1024 + t * 4;
        int ee = e0 + (f >> 9);
        if (ee >= n_edges) ee = n_edges - 1;
        const int o = f & 511;
        const int se = src[ee];
        const int de = dst[ee];
        const float4 kv = *reinterpret_cast<const float4*>(Kh + (size_t)se * 512 + o);
        const float4 qv = *reinterpret_cast<const float4*>(Qh + (size_t)de * 512 + o);
        const int r = f >> 6, c4 = (f & 63) >> 2;
        kt4[r * 17 + c4] = kv;
        qt4[r * 17 + c4] = qv;
    }
    __syncthreads();

    float acc[16];
    init16_bias(Eb + chunk * 16, acc);
    proj16_acc(et, lane, Ew + chunk * 16, acc);

    // score += K[src]*Q_scaled[dst] for this head's 16 dims (LDS b128 reads)
#pragma unroll
    for (int c4 = 0; c4 < 4; ++c4) {
        const float4 kv = kt4[lane * 17 + chunk * 4 + c4];
        const float4 qv = qt4[lane * 17 + chunk * 4 + c4];
        acc[c4 * 4 + 0] = fmaf(kv.x, qv.x, acc[c4 * 4 + 0]);
        acc[c4 * 4 + 1] = fmaf(kv.y, qv.y, acc[c4 * 4 + 1]);
        acc[c4 * 4 + 2] = fmaf(kv.z, qv.z, acc[c4 * 4 + 2]);
        acc[c4 * 4 + 3] = fmaf(kv.w, qv.w, acc[c4 * 4 + 3]);
    }

    // s = exp(clip(head sum)); s_buf layout [pair][head]
    {
        float s01 = (acc[0] + acc[1]) + (acc[2] + acc[3]);
        float s23 = (acc[4] + acc[5]) + (acc[6] + acc[7]);
        float s45 = (acc[8] + acc[9]) + (acc[10] + acc[11]);
        float s67 = (acc[12] + acc[13]) + (acc[14] + acc[15]);
        float ssum = (s01 + s23) + (s45 + s67);
        ssum = fminf(fmaxf(ssum, -5.f), 5.f);
        s_buf[(size_t)(p0 + lane) * N_HEADS + chunk] = __expf(ssum);
    }

    // transpose e_out through et -> coalesced stores
    __syncthreads();     // all waves done reading et/kt/qt
#pragma unroll
    for (int j = 0; j < 16; ++j) et[lane * 65 + chunk * 16 + j] = acc[j];
    __syncthreads();
#pragma unroll
    for (int i = 0; i < 4; ++i) {
        const int f = i * 1024 + t * 4;
        const int r = f >> 6, c = f & 63;
        *reinterpret_cast<float4*>(e_out + (size_t)p0 * 64 + f) =
            make_float4(et[r * 65 + c], et[r * 65 + c + 1],
                        et[r * 65 + c + 2], et[r * 65 + c + 3]);
    }
}

// ---------------------------------------------------------------------------
// Gather v4: one wave handles 4 toks of a node (2 waves/node).
//  - lane l: tok = tokbase + (l>>4), dims [(l&15)*4, +4) -> float4 V loads;
//    a wave's 64 lanes read ONE contiguous 1KB block of Vh per edge.
//  - s_buf [pair][head]: wave's 64 s-loads hit 16 consecutive floats.
//  - index walk shared by 4 toks (shfl broadcast), h_out stores float4.
// ---------------------------------------------------------------------------
__global__ void __launch_bounds__(256) gather_kernel(
    const float* __restrict__ Vh, const float* __restrict__ s_buf,
    const int* __restrict__ src,
    const int* __restrict__ offs, const int* __restrict__ csr,
    float* __restrict__ h_out, int n_nodes) {
    const int gid = blockIdx.x * 4 + (threadIdx.x >> 6);   // global wave id
    const int lane = threadIdx.x & 63;
    const int node = gid >> 1;
    if (node >= n_nodes) return;
    const int tok = ((gid & 1) << 2) + (lane >> 4);        // 0..7
    const int dim0 = (lane & 15) << 2;                     // 0,4,...,60
    const int soff = (tok << 2) + (dim0 >> 4);             // tok*4 + head
    const int voff = (tok << 6) + dim0;                    // within 8x64 node block
    const int beg = offs[node];
    const int end = offs[node + 1];
    float4 acc = make_float4(0.f, 0.f, 0.f, 0.f);
    float z = 0.f;
    for (int base = beg; base < end; base += 64) {
        const int nn = min(64, end - base);
        int eid = 0, sidx = 0;
        if (lane < nn) {
            eid = csr[base + lane];      // coalesced
            sidx = src[eid];             // lane-parallel random
        }
        int j = 0;
        for (; j + 1 < nn; j += 2) {
            const int ej0 = __shfl(eid, j),  ej1 = __shfl(eid, j + 1);
            const int sj0 = __shfl(sidx, j), sj1 = __shfl(sidx, j + 1);
            const float sh0 = s_buf[(size_t)ej0 * 32 + soff];
            const float sh1 = s_buf[(size_t)ej1 * 32 + soff];
            const float4 v0 = *reinterpret_cast<const float4*>(
                Vh + (size_t)sj0 * 512 + voff);
            const float4 v1 = *reinterpret_cast<const float4*>(
                Vh + (size_t)sj1 * 512 + voff);
            acc.x = fmaf(v0.x, sh0, acc.x);
            acc.y = fmaf(v0.y, sh0, acc.y);
            acc.z = fmaf(v0.z, sh0, acc.z);
            acc.w = fmaf(v0.w, sh0, acc.w);
            z += sh0;
            acc.x = fmaf(v1.x, sh1, acc.x);
            acc.y = fmaf(v1.y, sh1, acc.y);
            acc.z = fmaf(v1.z, sh1, acc.z);
            acc.w = fmaf(v1.w, sh1, acc.w);
            z += sh1;
        }
        if (j < nn) {
            const int ej = __shfl(eid, j);
            const int sj = __shfl(sidx, j);
            const float sh = s_buf[(size_t)ej * 32 + soff];
            const float4 v = *reinterpret_cast<const float4*>(
                Vh + (size_t)sj * 512 + voff);
            acc.x = fmaf(v.x, sh, acc.x);
            acc.y = fmaf(v.y, sh, acc.y);
            acc.z = fmaf(v.z, sh, acc.z);
            acc.w = fmaf(v.w, sh, acc.w);
            z += sh;
        }
    }
    const float inv = 1.f / (z + 1e-6f);
    *reinterpret_cast<float4*>(h_out + ((size_t)node * 8 + tok) * 64 + dim0) =
        make_float4(acc.x * inv, acc.y * inv, acc.z * inv, acc.w * inv);
}

// ---------------------------------------------------------------------------
extern "C" void kernel_launch(void* const* d_in, const int* in_sizes, int n_in,
                              void* d_out, int out_size, void* d_ws, size_t ws_size,
                              hipStream_t stream) {
    const float* h  = (const float*)d_in[0];
    const float* e  = (const float*)d_in[1];
    const int* src  = (const int*)d_in[2];
    const int* dst  = (const int*)d_in[3];
    const float* Qw = (const float*)d_in[4];
    const float* Qb = (const float*)d_in[5];
    const float* Kw = (const float*)d_in[6];
    const float* Kb = (const float*)d_in[7];
    const float* Vw = (const float*)d_in[8];
    const float* Vb = (const float*)d_in[9];
    const float* Ew = (const float*)d_in[10];
    const float* Eb = (const float*)d_in[11];

    const int n_nodes = in_sizes[0] / (N_TOK * IN_DIM);   // 20000
    const int n_edges = in_sizes[2];                      // 200000
    const int nrows   = n_nodes * N_TOK;                  // 160000
    const int npairs  = n_edges * N_TOK;                  // 1.6M
    const int h_out_elems = n_nodes * N_TOK * OUT_DIM;

    float* h_out = (float*)d_out;
    float* e_out = (float*)d_out + h_out_elems;

    float* Qh    = (float*)d_ws;
    float* Kh    = Qh + (size_t)nrows * OUT_DIM;
    float* Vh    = Kh + (size_t)nrows * OUT_DIM;
    float* s_buf = Vh + (size_t)nrows * OUT_DIM;          // [npairs][N_HEADS]
    int*   deg   = (int*)(s_buf + (size_t)npairs * N_HEADS);
    int*   offs  = deg + n_nodes;
    int*   cur   = offs + (n_nodes + 1);
    int*   csr   = cur + n_nodes;

    zero_kernel<<<(n_nodes + 255) / 256, 256, 0, stream>>>(deg, n_nodes);
    hist_kernel<<<(n_edges + 255) / 256, 256, 0, stream>>>(dst, deg, n_edges);
    scan_kernel<<<1, 1024, 0, stream>>>(deg, offs, cur, n_nodes);
    scatter_kernel<<<(n_edges + 255) / 256, 256, 0, stream>>>(dst, cur, csr, n_edges);

    hproj_kernel<<<(nrows + 63) / 64, 256, 0, stream>>>(
        h, Qw, Qb, Kw, Kb, Vw, Vb, Qh, Kh, Vh, nrows);

    edge_kernel<<<(npairs + 63) / 64, 256, 0, stream>>>(
        e, src, dst, Ew, Eb, Qh, Kh, e_out, s_buf, npairs, n_edges);

    // 2 waves per node (4 toks/wave), 4 waves per block
    gather_kernel<<<(n_nodes * 2 + 3) / 4, 256, 0, stream>>>(
        Vh, s_buf, src, offs, csr, h_out, n_nodes);
}